// Round 3
// baseline (12725.664 us; speedup 1.0000x reference)
//
#include <hip/hip_runtime.h>

#define BATCH 64
#define SEQ   512
#define INP   512
#define HID   1024
#define MAGIC 0x13570000u

// ============================================================================
// Phase 1: out[m][n] = sum_f X[m][f] * Wih[n][f] + bih[n] + bhh[n]
//   Unchanged: ~200us, near the fp32 vector roofline (219us floor).
// ============================================================================
__global__ __launch_bounds__(256) void xw_gemm(
    const float* __restrict__ X, const float* __restrict__ Wih,
    const float* __restrict__ bih, const float* __restrict__ bhh,
    float* __restrict__ out)
{
    __shared__ float As[8][128];
    __shared__ float Bs[8][128];
    const int t  = threadIdx.x;
    const int m0 = blockIdx.x * 128;
    const int n0 = blockIdx.y * 128;
    const int lr = t >> 1;           // 0..127 tile row for staging
    const int lk = (t & 1) * 4;      // 0 | 4
    const int ty = t >> 4;           // 0..15 (m micro position)
    const int tx = t & 15;           // 0..15 (n micro position)

    float acc[8][8];
#pragma unroll
    for (int i = 0; i < 8; ++i)
#pragma unroll
        for (int j = 0; j < 8; ++j) acc[i][j] = 0.f;

    const float* xrow = X   + (size_t)(m0 + lr) * INP + lk;
    const float* wrow = Wih + (size_t)(n0 + lr) * INP + lk;

    for (int k0 = 0; k0 < INP; k0 += 8) {
        float4 av = *(const float4*)(xrow + k0);
        float4 bv = *(const float4*)(wrow + k0);
        __syncthreads();   // previous tile's compute done before overwrite
        As[lk + 0][lr] = av.x; As[lk + 1][lr] = av.y;
        As[lk + 2][lr] = av.z; As[lk + 3][lr] = av.w;
        Bs[lk + 0][lr] = bv.x; Bs[lk + 1][lr] = bv.y;
        Bs[lk + 2][lr] = bv.z; Bs[lk + 3][lr] = bv.w;
        __syncthreads();
#pragma unroll
        for (int kk = 0; kk < 8; ++kk) {
            float4 a0 = *(const float4*)&As[kk][ty * 4];
            float4 a1 = *(const float4*)&As[kk][64 + ty * 4];
            float4 b0 = *(const float4*)&Bs[kk][tx * 4];
            float4 b1 = *(const float4*)&Bs[kk][64 + tx * 4];
            float am[8] = {a0.x, a0.y, a0.z, a0.w, a1.x, a1.y, a1.z, a1.w};
            float bn[8] = {b0.x, b0.y, b0.z, b0.w, b1.x, b1.y, b1.z, b1.w};
#pragma unroll
            for (int i = 0; i < 8; ++i)
#pragma unroll
                for (int j = 0; j < 8; ++j)
                    acc[i][j] = fmaf(am[i], bn[j], acc[i][j]);
        }
    }

    const int nA = n0 + tx * 4;
    const int nB = n0 + 64 + tx * 4;
    float4 bA1 = *(const float4*)(bih + nA);
    float4 bA2 = *(const float4*)(bhh + nA);
    float4 bB1 = *(const float4*)(bih + nB);
    float4 bB2 = *(const float4*)(bhh + nB);
    float4 biasA = make_float4(bA1.x + bA2.x, bA1.y + bA2.y, bA1.z + bA2.z, bA1.w + bA2.w);
    float4 biasB = make_float4(bB1.x + bB2.x, bB1.y + bB2.y, bB1.z + bB2.z, bB1.w + bB2.w);

#pragma unroll
    for (int i = 0; i < 8; ++i) {
        int mloc = (i < 4) ? (ty * 4 + i) : (64 + ty * 4 + (i - 4));
        size_t m = (size_t)(m0 + mloc);
        float4 vA = make_float4(acc[i][0] + biasA.x, acc[i][1] + biasA.y,
                                acc[i][2] + biasA.z, acc[i][3] + biasA.w);
        float4 vB = make_float4(acc[i][4] + biasB.x, acc[i][5] + biasB.y,
                                acc[i][6] + biasB.z, acc[i][7] + biasB.w);
        *(float4*)(out + m * HID + nA) = vA;
        *(float4*)(out + m * HID + nB) = vB;
    }
}

// ============================================================================
// Phase 2 v4: persistent sequential scan, in-place on out.
// 256 blocks = 4 batch-groups (16 batches) x 64 j-tiles (16 j), 512 threads.
// v4 = v3 + __launch_bounds__(512, 2).
//   v3 post-mortem: VGPR_Count=128 -> wreg[32] (128 VGPRs) SPILLED to scratch;
//   FETCH_SIZE exploded 668MB -> 9.1GB (scratch re-reads, 256KB/block/step),
//   VALUBusy fell to 10%. min-waves=2 is free (512 thr = 2 waves/SIMD always)
//   and raises the VGPR cap to 256, fitting the ~210-reg live set.
// Structure (validated-correct in v3, absmax passed):
//   - h[s-1] staged into 64KB LDS by one coalesced 8xfloat4-per-thread burst.
//   - Hlds XOR-swizzled (c ^ ((c>>5)&7)); measured bank conflicts = 0.
//   - W tile in registers (32 float4/lane, loop-invariant).
//   - 8 waves: k split 8-way (shfl_xor 8/16/32), parallel 32-lane epilogue,
//     xw prefetched under the flag poll.
// Sync scheme (magic flags, slots mod 8, agent scope) unchanged.
// ============================================================================
__global__ __launch_bounds__(512, 2) void rnn_scan(
    const float* __restrict__ Whh, float* __restrict__ out,
    unsigned* __restrict__ flags)
{
    __shared__ float4 Hlds[16][256];   // 64 KB static; col-swizzled (see above)

    const int t  = threadIdx.x;        // 0..511
    const int g  = blockIdx.x >> 6;    // batch group 0..3
    const int jt = blockIdx.x & 63;    // j tile 0..63

    const int lane = t & 63;
    const int w    = t >> 6;           // wave 0..7
    const int bq   = w >> 1;           // batch quad 0..3
    const int jh   = w & 1;            // j half 0..1
    const int kc   = lane >> 3;        // k chunk 0..7 (128 k = 32 f4 each)
    const int jl   = lane & 7;         // j within half
    const int row  = jh * 8 + jl;      // W row / j within tile, 0..15
    const int b4   = bq * 4;           // first batch (group-relative) of quad
    const int Lb   = kc * 32;          // f4 column base for this lane's chunk

    // ---- W fragment -> registers (one-time, loop-invariant, 128 VGPR) ----
    float4 wreg[32];
    {
        const float4* wsrc =
            (const float4*)(Whh + (size_t)(jt * 16 + row) * HID) + (size_t)Lb;
#pragma unroll
        for (int i = 0; i < 32; ++i) wreg[i] = wsrc[i];
    }

    // epilogue roles: lanes 0..31 of each wave, one (batch, j) value each
    const bool act = (lane < 32);
    const int  q   = kc & 3;           // batch within quad (lanes<32: q==kc)
    float* outp = out + ((size_t)(g * 16 + b4 + q) * SEQ) * HID + (jt * 16 + row);

    const float4* h0p = &Hlds[b4 + 0][Lb];
    const float4* h1p = &Hlds[b4 + 1][Lb];
    const float4* h2p = &Hlds[b4 + 2][Lb];
    const float4* h3p = &Hlds[b4 + 3][Lb];

    __syncthreads();

    for (int s = 0; s < SEQ; ++s) {
        // prefetch xw (written by phase 1; only this thread ever rewrites it,
        // at step s below). Latency hides under the flag poll.
        float xwv = 0.f;
        if (act) xwv = outp[(size_t)s * HID];

        float a0 = 0.f, a1 = 0.f, a2 = 0.f, a3 = 0.f;

        if (s > 0) {
            // ---- group barrier: all 64 j-tiles of group g finished s-1 ----
            if (t < 64) {
                const unsigned want = MAGIC + (unsigned)(s - 1);
                unsigned* f = flags + ((((s - 1) & 7) * 4 + g) * 64 + t);
                while (__hip_atomic_load(f, __ATOMIC_RELAXED, __HIP_MEMORY_SCOPE_AGENT) != want)
                    __builtin_amdgcn_s_sleep(1);
            }
            __syncthreads();
            __builtin_amdgcn_fence(__ATOMIC_ACQUIRE, "agent");  // kill stale cache

            // ---- stage h[s-1] for the group's 16 batches: 64KB coalesced ----
            {
                const float* hb = out + ((size_t)(g * 16) * SEQ + (s - 1)) * HID;
                float4 tmp[8];
#pragma unroll
                for (int i = 0; i < 8; ++i) {
                    int idx = i * 512 + t;            // 0..4095 f4 slots
                    tmp[i] = *(const float4*)(hb + (size_t)(idx >> 8) * (SEQ * HID)
                                                 + (size_t)(idx & 255) * 4);
                }
#pragma unroll
                for (int i = 0; i < 8; ++i) {
                    int idx = i * 512 + t;
                    int c   = idx & 255;
                    Hlds[idx >> 8][c ^ ((c >> 5) & 7)] = tmp[i];  // XOR swizzle
                }
            }
            __syncthreads();

            // ---- compute: 32 f4-iters, 16 fma each; swizzle-corrected reads
            //      (logical col kc*32+i lives at physical kc*32 + (i^kc)) ----
#pragma unroll
            for (int i = 0; i < 32; ++i) {
                const float4 w4 = wreg[i];
                const int sc = i ^ kc;
                const float4 x0 = h0p[sc];
                const float4 x1 = h1p[sc];
                const float4 x2 = h2p[sc];
                const float4 x3 = h3p[sc];
                a0 = fmaf(x0.x, w4.x, a0); a0 = fmaf(x0.y, w4.y, a0);
                a0 = fmaf(x0.z, w4.z, a0); a0 = fmaf(x0.w, w4.w, a0);
                a1 = fmaf(x1.x, w4.x, a1); a1 = fmaf(x1.y, w4.y, a1);
                a1 = fmaf(x1.z, w4.z, a1); a1 = fmaf(x1.w, w4.w, a1);
                a2 = fmaf(x2.x, w4.x, a2); a2 = fmaf(x2.y, w4.y, a2);
                a2 = fmaf(x2.z, w4.z, a2); a2 = fmaf(x2.w, w4.w, a2);
                a3 = fmaf(x3.x, w4.x, a3); a3 = fmaf(x3.y, w4.y, a3);
                a3 = fmaf(x3.z, w4.z, a3); a3 = fmaf(x3.w, w4.w, a3);
            }
            // ---- reduce k-chunk partials (kc = lane bits 3..5) ----
            a0 += __shfl_xor(a0, 8); a0 += __shfl_xor(a0, 16); a0 += __shfl_xor(a0, 32);
            a1 += __shfl_xor(a1, 8); a1 += __shfl_xor(a1, 16); a1 += __shfl_xor(a1, 32);
            a2 += __shfl_xor(a2, 8); a2 += __shfl_xor(a2, 16); a2 += __shfl_xor(a2, 32);
            a3 += __shfl_xor(a3, 8); a3 += __shfl_xor(a3, 16); a3 += __shfl_xor(a3, 32);
        }

        // ---- finalize: 32 lanes/wave, one tanh + one agent store each ----
        if (act) {
            float v = (q == 0) ? a0 : (q == 1) ? a1 : (q == 2) ? a2 : a3;
            v = tanhf(xwv + v);
            __hip_atomic_store(outp + (size_t)s * HID, v,
                               __ATOMIC_RELAXED, __HIP_MEMORY_SCOPE_AGENT);
        }
        __syncthreads();   // drains vmcnt(0): all block stores globally visible
        if (t == 0)
            __hip_atomic_store(flags + (((s & 7) * 4 + g) * 64 + jt),
                               MAGIC + (unsigned)s,
                               __ATOMIC_RELAXED, __HIP_MEMORY_SCOPE_AGENT);
    }
}

// ============================================================================
extern "C" void kernel_launch(void* const* d_in, const int* in_sizes, int n_in,
                              void* d_out, int out_size, void* d_ws, size_t ws_size,
                              hipStream_t stream)
{
    (void)in_sizes; (void)n_in; (void)out_size; (void)ws_size;
    const float* x   = (const float*)d_in[0];   // (64,512,512)
    const float* Wih = (const float*)d_in[1];   // (1024,512)
    const float* Whh = (const float*)d_in[2];   // (1024,1024)
    const float* bih = (const float*)d_in[3];   // (1024,)
    const float* bhh = (const float*)d_in[4];   // (1024,)
    float* out = (float*)d_out;                 // (64,512,1024)
    unsigned* flags = (unsigned*)d_ws;          // 8 KB of flag slots (poison-safe)

    dim3 g1(BATCH * SEQ / 128, HID / 128);      // (256, 8)
    xw_gemm<<<g1, 256, 0, stream>>>(x, Wih, bih, bhh, out);
    rnn_scan<<<256, 512, 0, stream>>>(Whh, out, flags);
}

// Round 4
// 10697.784 us; speedup vs baseline: 1.1896x; 1.1896x over previous
//
#include <hip/hip_runtime.h>

#define BATCH 64
#define SEQ   512
#define INP   512
#define HID   1024
#define MAGIC 0x13570000u

// ============================================================================
// Phase 1: out[m][n] = sum_f X[m][f] * Wih[n][f] + bih[n] + bhh[n]
//   Unchanged: ~200us, near the fp32 vector roofline (219us floor).
// ============================================================================
__global__ __launch_bounds__(256) void xw_gemm(
    const float* __restrict__ X, const float* __restrict__ Wih,
    const float* __restrict__ bih, const float* __restrict__ bhh,
    float* __restrict__ out)
{
    __shared__ float As[8][128];
    __shared__ float Bs[8][128];
    const int t  = threadIdx.x;
    const int m0 = blockIdx.x * 128;
    const int n0 = blockIdx.y * 128;
    const int lr = t >> 1;           // 0..127 tile row for staging
    const int lk = (t & 1) * 4;      // 0 | 4
    const int ty = t >> 4;           // 0..15 (m micro position)
    const int tx = t & 15;           // 0..15 (n micro position)

    float acc[8][8];
#pragma unroll
    for (int i = 0; i < 8; ++i)
#pragma unroll
        for (int j = 0; j < 8; ++j) acc[i][j] = 0.f;

    const float* xrow = X   + (size_t)(m0 + lr) * INP + lk;
    const float* wrow = Wih + (size_t)(n0 + lr) * INP + lk;

    for (int k0 = 0; k0 < INP; k0 += 8) {
        float4 av = *(const float4*)(xrow + k0);
        float4 bv = *(const float4*)(wrow + k0);
        __syncthreads();   // previous tile's compute done before overwrite
        As[lk + 0][lr] = av.x; As[lk + 1][lr] = av.y;
        As[lk + 2][lr] = av.z; As[lk + 3][lr] = av.w;
        Bs[lk + 0][lr] = bv.x; Bs[lk + 1][lr] = bv.y;
        Bs[lk + 2][lr] = bv.z; Bs[lk + 3][lr] = bv.w;
        __syncthreads();
#pragma unroll
        for (int kk = 0; kk < 8; ++kk) {
            float4 a0 = *(const float4*)&As[kk][ty * 4];
            float4 a1 = *(const float4*)&As[kk][64 + ty * 4];
            float4 b0 = *(const float4*)&Bs[kk][tx * 4];
            float4 b1 = *(const float4*)&Bs[kk][64 + tx * 4];
            float am[8] = {a0.x, a0.y, a0.z, a0.w, a1.x, a1.y, a1.z, a1.w};
            float bn[8] = {b0.x, b0.y, b0.z, b0.w, b1.x, b1.y, b1.z, b1.w};
#pragma unroll
            for (int i = 0; i < 8; ++i)
#pragma unroll
                for (int j = 0; j < 8; ++j)
                    acc[i][j] = fmaf(am[i], bn[j], acc[i][j]);
        }
    }

    const int nA = n0 + tx * 4;
    const int nB = n0 + 64 + tx * 4;
    float4 bA1 = *(const float4*)(bih + nA);
    float4 bA2 = *(const float4*)(bhh + nA);
    float4 bB1 = *(const float4*)(bih + nB);
    float4 bB2 = *(const float4*)(bhh + nB);
    float4 biasA = make_float4(bA1.x + bA2.x, bA1.y + bA2.y, bA1.z + bA2.z, bA1.w + bA2.w);
    float4 biasB = make_float4(bB1.x + bB2.x, bB1.y + bB2.y, bB1.z + bB2.z, bB1.w + bB2.w);

#pragma unroll
    for (int i = 0; i < 8; ++i) {
        int mloc = (i < 4) ? (ty * 4 + i) : (64 + ty * 4 + (i - 4));
        size_t m = (size_t)(m0 + mloc);
        float4 vA = make_float4(acc[i][0] + biasA.x, acc[i][1] + biasA.y,
                                acc[i][2] + biasA.z, acc[i][3] + biasA.w);
        float4 vB = make_float4(acc[i][4] + biasB.x, acc[i][5] + biasB.y,
                                acc[i][6] + biasB.z, acc[i][7] + biasB.w);
        *(float4*)(out + m * HID + nA) = vA;
        *(float4*)(out + m * HID + nB) = vB;
    }
}

// ============================================================================
// Phase 2 v5: persistent sequential scan, in-place on out.
// 256 blocks = 4 batch-groups (16 batches) x 64 j-tiles (16 j), 512 threads.
// v4 post-mortem: launch_bounds(512,2) did NOT raise the 128-VGPR cap;
// wreg[32] (128 regs alone) kept spilling (FETCH 9.1GB, VALUBusy 10%).
// v5 restructures to fit <=128 live regs BY CONSTRUCTION:
//   - per-lane work: 2 j-rows x 8 batches x 32 k  (was 1 x 4 x 128)
//     -> W in regs = 16 float4 = 64 VGPR (was 128); acc = 16.
//     -> each h float4 feeds 8 FMAs (was 4): halves LDS instruction count.
//   - lane k-subset INTERLEAVED ({i*32+kc}): each iter the wave reads 32
//     consecutive float4 from Hlds (pairs broadcast) -> conflict-free with a
//     LINEAR Hlds, no swizzle. Staging writes stay linear/conflict-free.
//   - reduction: xor-butterfly over lane bits 1..5 (distances 2..32);
//     epilogue 8-way select via constant-index cndmask tree (no rule-#20).
//   - amdgpu_waves_per_eu(2,2): pins 2 waves/SIMD (what a 512-thr block needs
//     anyway) -> VGPR cap 256, belt-and-braces against spill.
// h[s-1] staged into 64KB LDS by coalesced 8xfloat4/thread burst (as v3/v4).
// Sync scheme (magic flags, slots mod 8, agent scope) unchanged & proven.
// ============================================================================
__global__ __launch_bounds__(512) __attribute__((amdgpu_waves_per_eu(2, 2)))
void rnn_scan(
    const float* __restrict__ Whh, float* __restrict__ out,
    unsigned* __restrict__ flags)
{
    __shared__ float4 Hlds[16][256];   // 64 KB static, LINEAR layout

    const int t  = threadIdx.x;        // 0..511
    const int g  = blockIdx.x >> 6;    // batch group 0..3
    const int jt = blockIdx.x & 63;    // j tile 0..63

    const int lane = t & 63;
    const int w    = t >> 6;           // wave 0..7
    const int jq   = w >> 1;           // j quad 0..3 -> rows jq*4 .. jq*4+3
    const int bo   = w & 1;            // batch octet 0..1
    const int kc   = lane >> 1;        // k slot 0..31
    const int jl   = lane & 1;         // row parity
    const int r0   = jq * 4 + jl;      // lane's first row (0..15 within tile)
    const int r1   = r0 + 2;           // lane's second row
    const int b8   = bo * 8;           // group-relative batch base

    // ---- W rows r0,r1, interleaved k-slices -> registers (64 VGPR) ----
    // lane's k-subset (f4 units): { i*32 + kc : i = 0..7 }
    float4 wA[8], wB[8];
    {
        const float4* s0 = (const float4*)(Whh + (size_t)(jt * 16 + r0) * HID);
        const float4* s1 = (const float4*)(Whh + (size_t)(jt * 16 + r1) * HID);
#pragma unroll
        for (int i = 0; i < 8; ++i) {
            wA[i] = s0[i * 32 + kc];
            wB[i] = s1[i * 32 + kc];
        }
    }

    // epilogue roles: lanes 0..31, one (batch, row) value each.
    // lane bits: 0 = row parity (must equal jl: true for own lane), 1 = A/B
    // family (row +0 / +2), 2..4 = batch within octet.
    const bool act = (lane < 32);
    const int  n   = (lane >> 2) & 7;          // batch within octet
    const int  rs  = (lane >> 1) & 1;          // 0 -> aA (r0), 1 -> aB (r1)
    const int  ro  = rs * 2 + (lane & 1);      // row within quad 0..3
    float* outp = out + ((size_t)(g * 16 + b8 + n) * SEQ) * HID
                      + (jt * 16 + jq * 4 + ro);

    __syncthreads();

    for (int s = 0; s < SEQ; ++s) {
        // prefetch xw (phase-1 data; only this thread rewrites it, at step s).
        float xwv = 0.f;
        if (act) xwv = outp[(size_t)s * HID];

        float aA[8] = {0, 0, 0, 0, 0, 0, 0, 0};
        float aB[8] = {0, 0, 0, 0, 0, 0, 0, 0};

        if (s > 0) {
            // ---- group barrier: all 64 j-tiles of group g finished s-1 ----
            if (t < 64) {
                const unsigned want = MAGIC + (unsigned)(s - 1);
                unsigned* f = flags + ((((s - 1) & 7) * 4 + g) * 64 + t);
                while (__hip_atomic_load(f, __ATOMIC_RELAXED, __HIP_MEMORY_SCOPE_AGENT) != want)
                    __builtin_amdgcn_s_sleep(1);
            }
            __syncthreads();
            __builtin_amdgcn_fence(__ATOMIC_ACQUIRE, "agent");  // kill stale cache

            // ---- stage h[s-1] for the group's 16 batches: 64KB coalesced ----
            {
                const float* hb = out + ((size_t)(g * 16) * SEQ + (s - 1)) * HID;
                float4 tmp[8];
#pragma unroll
                for (int i = 0; i < 8; ++i) {
                    int idx = i * 512 + t;            // 0..4095 f4 slots
                    tmp[i] = *(const float4*)(hb + (size_t)(idx >> 8) * (SEQ * HID)
                                                 + (size_t)(idx & 255) * 4);
                }
#pragma unroll
                for (int i = 0; i < 8; ++i) {
                    int idx = i * 512 + t;
                    Hlds[idx >> 8][idx & 255] = tmp[i];   // linear, conflict-free
                }
            }
            __syncthreads();

            // ---- compute: 8 iters; 8 consecutive-f4 LDS reads feed 64 FMA --
#define DOT4(ACC, X, U) \
    ACC = fmaf((X).x, (U).x, ACC); ACC = fmaf((X).y, (U).y, ACC); \
    ACC = fmaf((X).z, (U).z, ACC); ACC = fmaf((X).w, (U).w, ACC);
#pragma unroll
            for (int i = 0; i < 8; ++i) {
                const int c = i * 32 + kc;         // wave: 32 consecutive f4
                const float4 u = wA[i];
                const float4 v = wB[i];
                float4 x0 = Hlds[b8 + 0][c];
                float4 x1 = Hlds[b8 + 1][c];
                float4 x2 = Hlds[b8 + 2][c];
                float4 x3 = Hlds[b8 + 3][c];
                DOT4(aA[0], x0, u) DOT4(aB[0], x0, v)
                DOT4(aA[1], x1, u) DOT4(aB[1], x1, v)
                DOT4(aA[2], x2, u) DOT4(aB[2], x2, v)
                DOT4(aA[3], x3, u) DOT4(aB[3], x3, v)
                float4 x4 = Hlds[b8 + 4][c];
                float4 x5 = Hlds[b8 + 5][c];
                float4 x6 = Hlds[b8 + 6][c];
                float4 x7 = Hlds[b8 + 7][c];
                DOT4(aA[4], x4, u) DOT4(aB[4], x4, v)
                DOT4(aA[5], x5, u) DOT4(aB[5], x5, v)
                DOT4(aA[6], x6, u) DOT4(aB[6], x6, v)
                DOT4(aA[7], x7, u) DOT4(aB[7], x7, v)
            }
#undef DOT4

            // ---- reduce over kc (lane bits 1..5), rows stay separate ------
#pragma unroll
            for (int j = 0; j < 8; ++j) {
                aA[j] += __shfl_xor(aA[j], 2);  aB[j] += __shfl_xor(aB[j], 2);
                aA[j] += __shfl_xor(aA[j], 4);  aB[j] += __shfl_xor(aB[j], 4);
                aA[j] += __shfl_xor(aA[j], 8);  aB[j] += __shfl_xor(aB[j], 8);
                aA[j] += __shfl_xor(aA[j], 16); aB[j] += __shfl_xor(aB[j], 16);
                aA[j] += __shfl_xor(aA[j], 32); aB[j] += __shfl_xor(aB[j], 32);
            }
        }

        // ---- finalize: 32 lanes/wave, one tanh + one agent store each ----
        if (act) {
            // constant-index select tree (no runtime array indexing)
            float sA0 = (n & 1) ? aA[1] : aA[0];
            float sA1 = (n & 1) ? aA[3] : aA[2];
            float sA2 = (n & 1) ? aA[5] : aA[4];
            float sA3 = (n & 1) ? aA[7] : aA[6];
            float sB0 = (n & 1) ? aB[1] : aB[0];
            float sB1 = (n & 1) ? aB[3] : aB[2];
            float sB2 = (n & 1) ? aB[5] : aB[4];
            float sB3 = (n & 1) ? aB[7] : aB[6];
            float tA0 = (n & 2) ? sA1 : sA0;
            float tA1 = (n & 2) ? sA3 : sA2;
            float tB0 = (n & 2) ? sB1 : sB0;
            float tB1 = (n & 2) ? sB3 : sB2;
            float vA  = (n & 4) ? tA1 : tA0;
            float vB  = (n & 4) ? tB1 : tB0;
            float v   = rs ? vB : vA;
            v = tanhf(xwv + v);
            __hip_atomic_store(outp + (size_t)s * HID, v,
                               __ATOMIC_RELAXED, __HIP_MEMORY_SCOPE_AGENT);
        }
        __syncthreads();   // drains vmcnt(0): all block stores globally visible
        if (t == 0)
            __hip_atomic_store(flags + (((s & 7) * 4 + g) * 64 + jt),
                               MAGIC + (unsigned)s,
                               __ATOMIC_RELAXED, __HIP_MEMORY_SCOPE_AGENT);
    }
}

// ============================================================================
extern "C" void kernel_launch(void* const* d_in, const int* in_sizes, int n_in,
                              void* d_out, int out_size, void* d_ws, size_t ws_size,
                              hipStream_t stream)
{
    (void)in_sizes; (void)n_in; (void)out_size; (void)ws_size;
    const float* x   = (const float*)d_in[0];   // (64,512,512)
    const float* Wih = (const float*)d_in[1];   // (1024,512)
    const float* Whh = (const float*)d_in[2];   // (1024,1024)
    const float* bih = (const float*)d_in[3];   // (1024,)
    const float* bhh = (const float*)d_in[4];   // (1024,)
    float* out = (float*)d_out;                 // (64,512,1024)
    unsigned* flags = (unsigned*)d_ws;          // 8 KB of flag slots (poison-safe)

    dim3 g1(BATCH * SEQ / 128, HID / 128);      // (256, 8)
    xw_gemm<<<g1, 256, 0, stream>>>(x, Wih, bih, bhh, out);
    rnn_scan<<<256, 512, 0, stream>>>(Whh, out, flags);
}